// Round 8
// baseline (8105.899 us; speedup 1.0000x reference)
//
#include <hip/hip_runtime.h>
#include <hip/hip_cooperative_groups.h>
namespace cg = cooperative_groups;

typedef unsigned int  u32;
typedef unsigned short u16;
typedef float v2f __attribute__((ext_vector_type(2)));

// B=8, NS=80, NN=81, H=256, L=2, STEPS=8, VOCAB=30000
#define ROWS 648          // B*NN

__device__ __forceinline__ float sigf(float x){ return 1.0f/(1.0f+__expf(-x)); }
__device__ __forceinline__ float tanh_fast(float x){
  float e = __expf(-2.0f*fabsf(x));
  float r = (1.0f-e)/(1.0f+e);
  return copysignf(r,x);
}
__device__ __forceinline__ u16 f2bf(float f){        // RTNE f32->bf16
  u32 u = __float_as_uint(f);
  u += 0x7FFFu + ((u>>16)&1u);
  return (u16)(u>>16);
}
__device__ __forceinline__ u32 packbf2(float lo, float hi){
  return (u32)f2bf(lo) | ((u32)f2bf(hi)<<16);
}
__device__ __forceinline__ float bf2f(u16 v){ return __uint_as_float(((u32)v)<<16); }
__device__ __forceinline__ float bflo(u32 u){ return __uint_as_float(u<<16); }
__device__ __forceinline__ float bfhi(u32 u){ return __uint_as_float(u & 0xFFFF0000u); }
__device__ __forceinline__ v2f unpk(u32 w){
  v2f r; r.x = bflo(w); r.y = bfhi(w); return r;
}

// ---------------- weight packing ----------------------------------------
__global__ void pack_gates(const float* __restrict__ A, const float* __restrict__ Bm,
                           u32* __restrict__ dst, int Krows){
  int id = blockIdx.x*256 + threadIdx.x;
  int tot = (Krows>>1)*1024;
  if (id >= tot) return;
  int k2 = id >> 10;
  int c  = id & 1023;
  int j = c >> 2, g = c & 3;
  int k0 = 2*k2, k1 = 2*k2+1;
  float v0 = (k0<256) ? A[k0*1024 + g*256 + j] : Bm[(k0-256)*1024 + g*256 + j];
  float v1 = (k1<256) ? A[k1*1024 + g*256 + j] : Bm[(k1-256)*1024 + g*256 + j];
  dst[id] = packbf2(v0, v1);
}

__global__ void pack_gates_sc(const float* __restrict__ A, const float* __restrict__ Bm,
                              const float* __restrict__ scA, const float* __restrict__ scB,
                              u32* __restrict__ dst, int Krows){
  int id = blockIdx.x*256 + threadIdx.x;
  int tot = (Krows>>1)*1024;
  if (id >= tot) return;
  int k2 = id >> 10;
  int c  = id & 1023;
  int j = c >> 2, g = c & 3;
  int k0 = 2*k2, k1 = 2*k2+1;
  float v0, v1;
  if (k0 < 256){ v0 = A[k0*1024 + g*256 + j];        if (scA) v0 *= scA[k0]; }
  else         { v0 = Bm[(k0-256)*1024 + g*256 + j]; if (scB) v0 *= scB[k0-256]; }
  if (k1 < 256){ v1 = A[k1*1024 + g*256 + j];        if (scA) v1 *= scA[k1]; }
  else         { v1 = Bm[(k1-256)*1024 + g*256 + j]; if (scB) v1 *= scB[k1-256]; }
  dst[id] = packbf2(v0, v1);
}

__global__ void pack_pairs(const float* __restrict__ src, u32* __restrict__ dst,
                           int Kpairs, int ncol){
  int id = blockIdx.x*256 + threadIdx.x;
  if (id >= Kpairs*ncol) return;
  int k2 = id / ncol, j = id - k2*ncol;
  dst[id] = packbf2(src[(2*k2)*ncol + j], src[(2*k2+1)*ncol + j]);
}

__global__ void k_init_p(float* __restrict__ p0){
  int i = blockIdx.x*256 + threadIdx.x;
  if (i < ROWS) p0[i] = ((i % 81)==0) ? 1.0f : 0.0f;
}

// LN-fold constants (float layout): u0 | v0(+1024) | u1(+2048) | v1(+3072) | cb1(+4096)
__global__ void k_uv(const float* __restrict__ Wh0, const float* __restrict__ Wh1,
                     const float* __restrict__ lnS, const float* __restrict__ lnB,
                     const float* __restrict__ skb, float* __restrict__ uv){
  int id = blockIdx.x*256 + threadIdx.x;       // 0..1023
  int g = id & 3, jh = id >> 2;
  float u0=0,v0=0,u1=0,v1=0;
  for (int k=0;k<256;k++){
    float w0 = Wh0[k*1024 + g*256 + jh];
    u0 = fmaf(lnS[256+k], w0, u0); v0 = fmaf(lnB[256+k], w0, v0);
    float w1 = Wh1[k*1024 + g*256 + jh];
    u1 = fmaf(lnS[768+k], w1, u1); v1 = fmaf(lnB[768+k], w1, v1);
  }
  uv[id]=u0; uv[1024+id]=v0; uv[2048+id]=u1; uv[3072+id]=v1;
  uv[4096+id]=skb[1024 + g*256 + jh];
}

// ---------------- K1: statement embedder + X0 precompute ----------------
__global__ __launch_bounds__(512) void k_stmt_x0(
    const float* __restrict__ ne, const float* __restrict__ stWx, const float* __restrict__ stb,
    const float* __restrict__ skWx, const float* __restrict__ skb, float4* __restrict__ X0){
  __shared__ float xv[2][256];
  __shared__ float hv[2][256];
  int r = threadIdx.x >> 8, j = threadIdx.x & 255;
  int bn = blockIdx.x*2 + r;                    // 0..639
  xv[r][j] = ne[bn*256 + j];
  __syncthreads();
  float a0=stb[j], a2=stb[512+j], a3=stb[768+j];
  for (int k=0;k<256;k++){
    float x = xv[r][k];
    const float* w = stWx + k*1024;
    a0 = fmaf(x, w[j], a0); a2 = fmaf(x, w[512+j], a2); a3 = fmaf(x, w[768+j], a3);
  }
  float c = sigf(a0)*tanh_fast(a2);
  float h = sigf(a3)*tanh_fast(c);
  hv[r][j] = h;
  __syncthreads();
  a0=stb[1024+j]; a2=stb[1536+j]; a3=stb[1792+j];
  const float* W1 = stWx + 256*1024;
  for (int k=0;k<256;k++){
    float x = hv[r][k];
    const float* w = W1 + k*1024;
    a0 = fmaf(x, w[j], a0); a2 = fmaf(x, w[512+j], a2); a3 = fmaf(x, w[768+j], a3);
  }
  c = sigf(a0)*tanh_fast(a2);
  h = sigf(a3)*tanh_fast(c);
  __syncthreads();
  xv[r][j] = h;           // stmt row
  __syncthreads();
  float b0=skb[j], b1g=skb[256+j], b2=skb[512+j], b3=skb[768+j];
  for (int k=0;k<256;k++){
    float x = xv[r][k];
    const float* w = skWx + k*1024;
    b0 = fmaf(x, w[j], b0);     b1g = fmaf(x, w[256+j], b1g);
    b2 = fmaf(x, w[512+j], b2); b3 = fmaf(x, w[768+j], b3);
  }
  X0[bn*256 + j] = make_float4(b0,b1g,b2,b3);
}

// ---------------- cooperative wavefront skip-encoder ---------------------
// ONE kernel, 80 steps x 2 phases, grid sync between phases.
// 256 blocks x 512 thr; block = (j-slice jp of 16 cols, row-group rg of 40).
// W slices LDS-resident (96 KB), loaded once. c0/c1 states in registers.
// LN folded: h_ln@W = rstd*(h_raw@diag(lnS)W) - rstd*mu*u + v.
__global__ __launch_bounds__(512, 2) void k_chain_coop(
    const float4* __restrict__ X0,
    const uint4* __restrict__ W0p, const uint4* __restrict__ W1p,
    const float4* __restrict__ uv4, const float* __restrict__ lnS, const float* __restrict__ lnB,
    float* __restrict__ H0a, float* __restrict__ H0b,
    float* __restrict__ H1a, float* __restrict__ H1b,
    float* __restrict__ stats, float* __restrict__ skip){
  cg::grid_group grid = cg::this_grid();
  int blk = blockIdx.x;
  int jp = blk & 15;          // j-slice
  int rg = blk >> 4;          // row-group (40 rows)
  int t = threadIdx.x;
  int jl = t & 15;
  int jh = jp*16 + jl;
  __shared__ uint4 W0l[2048];   // 32 KB: [k2*16 + jl]
  __shared__ uint4 W1l[4096];   // 64 KB
  for (int e = t; e < 2048; e += 512) W0l[e] = W0p[(e>>4)*256 + jp*16 + (e&15)];
  for (int e = t; e < 4096; e += 512) W1l[e] = W1p[(e>>4)*256 + jp*16 + (e&15)];
  __syncthreads();
  // per-jh constants (same for both cells of this thread)
  float4 u0 = uv4[jh],     v0 = uv4[256+jh];
  float4 u1 = uv4[512+jh], v1 = uv4[768+jh];
  float4 cb = uv4[1024+jh];
  float lc0s = lnS[jh],     lc0b = lnB[jh];
  float lc1s = lnS[512+jh], lc1b = lnB[512+jh];
  // cells: cell0 row-local rl0 = t>>4 (0..31); cell1 rl0+32 (only t<128)
  int rl0 = t >> 4;
  int ncell = (t < 128) ? 2 : 1;
  float c0[2] = {0.f,0.f}, c1[2] = {0.f,0.f};
  float h0v[2];

  for (int idx = 0; idx < 80; idx++){
    const float* H0prev = (idx&1) ? H0a : H0b;
    float*       H0cur  = (idx&1) ? H0b : H0a;
    const float* H1prev = (idx&1) ? H1a : H1b;
    float*       H1cur  = (idx&1) ? H1b : H1a;
    // ---- phase A: layer0
    for (int cc = 0; cc < ncell; cc++){
      int r = rg*40 + rl0 + cc*32;
      int s = r >> 3, b = r & 7;
      if (s > idx) continue;
      bool start = (s == idx);
      float4 x0 = X0[(b*80 + idx)*256 + jh];
      float a0,a1,a2,a3, mu=0.f, rstd=0.f;
      if (start){ a0=x0.x; a1=x0.y; a2=x0.z; a3=x0.w; }
      else {
        float smv = stats[((idx-1)*640 + r)*2+0];
        float sqv = stats[((idx-1)*640 + r)*2+1];
        mu = smv*(1.f/1024.f);
        float var = sqv*(1.f/1024.f) - mu*mu;
        rstd = rsqrtf(var + 1e-6f);
        v2f A0={0,0},A1={0,0},A2={0,0},A3={0,0};
        const float* hrow = H0prev + r*256;
        #pragma unroll 8
        for (int k2=0;k2<128;k2++){
          uint4 w = W0l[k2*16 + jl];
          v2f hp = *(const v2f*)&hrow[2*k2];
          A0 += hp*unpk(w.x); A1 += hp*unpk(w.y);
          A2 += hp*unpk(w.z); A3 += hp*unpk(w.w);
        }
        float rm = rstd*mu;
        a0 = x0.x + rstd*(A0.x+A0.y) - rm*u0.x + v0.x;
        a1 = x0.y + rstd*(A1.x+A1.y) - rm*u0.y + v0.y;
        a2 = x0.z + rstd*(A2.x+A2.y) - rm*u0.z + v0.z;
        a3 = x0.w + rstd*(A3.x+A3.y) - rm*u0.w + v0.w;
      }
      float c0ln = start ? 0.f : (c0[cc]-mu)*rstd*lc0s + lc0b;
      float ii=sigf(a0), ff=sigf(a1), gg=tanh_fast(a2), oo=sigf(a3);
      float cn = ff*c0ln + ii*gg;
      c0[cc] = cn;
      float hn = oo*tanh_fast(cn);
      h0v[cc] = hn;
      H0cur[r*256 + jh] = hn;
    }
    grid.sync();
    // ---- phase B: layer1 + skip + stats
    for (int cc = 0; cc < ncell; cc++){
      int r = rg*40 + rl0 + cc*32;
      int s = r >> 3, b = r & 7;
      if (s > idx) continue;
      bool start = (s == idx);
      float mu=0.f, rstd=0.f;
      if (!start){
        float smv = stats[((idx-1)*640 + r)*2+0];
        float sqv = stats[((idx-1)*640 + r)*2+1];
        mu = smv*(1.f/1024.f);
        float var = sqv*(1.f/1024.f) - mu*mu;
        rstd = rsqrtf(var + 1e-6f);
      }
      v2f A0={0,0},A1={0,0},A2={0,0},A3={0,0};
      const float* h0row = H0cur + r*256;
      #pragma unroll 8
      for (int k2=0;k2<128;k2++){
        uint4 w = W1l[k2*16 + jl];
        v2f hp = *(const v2f*)&h0row[2*k2];
        A0 += hp*unpk(w.x); A1 += hp*unpk(w.y);
        A2 += hp*unpk(w.z); A3 += hp*unpk(w.w);
      }
      float a0 = A0.x+A0.y + cb.x;
      float a1 = A1.x+A1.y + cb.y;
      float a2 = A2.x+A2.y + cb.z;
      float a3 = A3.x+A3.y + cb.w;
      if (!start){
        v2f B0={0,0},B1={0,0},B2={0,0},B3={0,0};
        const float* h1row = H1prev + r*256;
        #pragma unroll 8
        for (int k2=0;k2<128;k2++){
          uint4 w = W1l[(128+k2)*16 + jl];
          v2f hp = *(const v2f*)&h1row[2*k2];
          B0 += hp*unpk(w.x); B1 += hp*unpk(w.y);
          B2 += hp*unpk(w.z); B3 += hp*unpk(w.w);
        }
        float rm = rstd*mu;
        a0 += rstd*(B0.x+B0.y) - rm*u1.x + v1.x;
        a1 += rstd*(B1.x+B1.y) - rm*u1.y + v1.y;
        a2 += rstd*(B2.x+B2.y) - rm*u1.z + v1.z;
        a3 += rstd*(B3.x+B3.y) - rm*u1.w + v1.w;
      }
      float c1ln = start ? 0.f : (c1[cc]-mu)*rstd*lc1s + lc1b;
      float ii=sigf(a0), ff=sigf(a1), gg=tanh_fast(a2), oo=sigf(a3);
      float cn = ff*c1ln + ii*gg;
      c1[cc] = cn;
      float hn = oo*tanh_fast(cn);
      H1cur[r*256 + jh] = hn;
      skip[((b*81 + s)*81 + (idx+1))*256 + jh] = hn;   // pre-LN output
      float sm = c0[cc] + h0v[cc] + cn + hn;
      float sq = c0[cc]*c0[cc] + h0v[cc]*h0v[cc] + cn*cn + hn*hn;
      #pragma unroll
      for (int off=8; off; off>>=1){ sm += __shfl_xor(sm, off); sq += __shfl_xor(sq, off); }
      if (jl == 0){
        atomicAdd(&stats[(idx*640 + r)*2+0], sm);
        atomicAdd(&stats[(idx*640 + r)*2+1], sq);
      }
    }
    grid.sync();
  }
}

// ---------------- K4: keys = skip @ ws + bs  (bf16 out) ------------------
__global__ __launch_bounds__(256) void k_keys(const float* __restrict__ skip,
    const u32* __restrict__ wspk, const float* __restrict__ bs, u16* __restrict__ keys){
  __shared__ float skr[8][256];
  int tid = threadIdx.x;
  int bn = blockIdx.x;
  float bsv = bs[tid];
  const float4* sk4 = (const float4*)skip;
  for (int m0=0; m0<81; m0+=8){
    int mc = (81-m0 < 8) ? (81-m0) : 8;
    for (int i=tid; i<mc*64; i+=256){
      int mm = i>>6, kk = i&63;
      float4 v = sk4[(bn*81 + m0 + mm)*64 + kk];
      skr[mm][4*kk+0]=v.x; skr[mm][4*kk+1]=v.y; skr[mm][4*kk+2]=v.z; skr[mm][4*kk+3]=v.w;
    }
    __syncthreads();
    v2f acc[8];
    #pragma unroll
    for (int qq=0;qq<8;qq++) acc[qq]=(v2f){0.f,0.f};
    for (int k2=0;k2<128;k2++){
      v2f w2 = unpk(wspk[k2*256+tid]);
      #pragma unroll
      for (int qq=0;qq<8;qq++){
        v2f sv = *(const v2f*)&skr[qq][2*k2];
        acc[qq] += sv*w2;
      }
    }
    for (int qq=0;qq<mc;qq++) keys[(bn*81+m0+qq)*256+tid] = f2bf(acc[qq].x+acc[qq].y+bsv);
    __syncthreads();
  }
}

// ---------------- Kb: fused q + logits -> softmax -> t -------------------
__global__ __launch_bounds__(256) void k_attn(
    const float* __restrict__ c0g, const float* __restrict__ h0g,
    const float* __restrict__ c1g, const float* __restrict__ h1g,
    const u32* __restrict__ wkp, const float* __restrict__ bk,
    const u16* __restrict__ keys, const float* __restrict__ w1,
    const float* __restrict__ pcur, float* __restrict__ t, int mode){
  int bn = blockIdx.x; int n = bn % 81;
  int tid = threadIdx.x;
  float pv = pcur[bn];
  if (pv == 0.0f){
    if (tid < 81) t[bn*81 + tid] = 0.0f;
    return;
  }
  __shared__ float hc[1024];
  __shared__ float qv[256];
  __shared__ float lg[81];
  hc[tid]      = c0g[bn*256+tid];
  hc[256+tid]  = h0g[bn*256+tid];
  hc[512+tid]  = c1g[bn*256+tid];
  hc[768+tid]  = h1g[bn*256+tid];
  if (tid < 81) lg[tid] = -3e38f;
  __syncthreads();
  v2f A = {bk[tid], 0.f};
  #pragma unroll 8
  for (int k2=0;k2<512;k2++){
    v2f hp = *(const v2f*)&hc[2*k2];
    A += hp*unpk(wkp[k2*256+tid]);
  }
  qv[tid] = A.x + A.y;
  __syncthreads();
  int lane = tid & 63, wv = tid >> 6;
  float w1v0 = w1[lane], w1v1 = w1[64+lane], w1v2 = w1[128+lane], w1v3 = w1[192+lane];
  for (int m = wv; m < 81; m += 4){
    bool um = (mode==0) ? (m==1) : (mode==2) ? (m==80) : (m>n || m==80);
    if (!um) continue;
    const u16* kr = keys + (bn*81+m)*256;
    float acc;
    acc  = tanh_fast(qv[lane]     + bf2f(kr[lane]))     * w1v0;
    acc += tanh_fast(qv[64+lane]  + bf2f(kr[64+lane]))  * w1v1;
    acc += tanh_fast(qv[128+lane] + bf2f(kr[128+lane])) * w1v2;
    acc += tanh_fast(qv[192+lane] + bf2f(kr[192+lane])) * w1v3;
    #pragma unroll
    for (int off=32; off; off>>=1) acc += __shfl_xor(acc, off);
    if (lane==0) lg[m] = acc;      // b1 omitted: softmax-invariant
  }
  __syncthreads();
  if (tid < 64){
    float v1 = lg[tid];
    float v2 = (tid<17) ? lg[64+tid] : -3e38f;
    float mx = fmaxf(v1, v2);
    #pragma unroll
    for (int off=32; off; off>>=1) mx = fmaxf(mx, __shfl_xor(mx, off));
    float e1 = __expf(v1-mx);
    float e2 = (tid<17) ? __expf(v2-mx) : 0.0f;
    float ssum = e1+e2;
    #pragma unroll
    for (int off=32; off; off>>=1) ssum += __shfl_xor(ssum, off);
    float sc = pv / ssum;
    t[bn*81 + tid] = e1*sc;
    if (tid<17) t[bn*81 + 64+tid] = e2*sc;
  }
}

// ---------------- Kc: x_in/prop einsums + ex-LSTM step + new_p -----------
__global__ __launch_bounds__(1024) void k_update(
    const float* __restrict__ t, const float* __restrict__ skip,
    const float* __restrict__ c0i, const float* __restrict__ h0i,
    const float* __restrict__ c1i, const float* __restrict__ h1i,
    const uint4* __restrict__ WA, const uint4* __restrict__ WB,
    const float* __restrict__ exb,
    float* __restrict__ c0o, float* __restrict__ h0o,
    float* __restrict__ c1o, float* __restrict__ h1o,
    float* __restrict__ pnext){
  int rr = threadIdx.x >> 8, j = threadIdx.x & 255;
  int row = blockIdx.x*4 + rr;
  int b = row / 81, m = row - b*81;
  __shared__ float tcol[4][81];
  __shared__ float xh[4][512];
  if (j < 81) tcol[rr][j] = t[(b*81 + j)*81 + m];
  __syncthreads();
  float xa=0.f, c0p=0.f, h0p=0.f, c1p=0.f, h1p=0.f, ts=0.f;
  for (int n=0;n<81;n++){
    float tv = tcol[rr][n];
    ts += tv;
    if (tv != 0.0f){
      xa  = fmaf(tv, skip[((b*81+n)*81 + m)*256 + j], xa);
      int st = (b*81+n)*256 + j;
      c0p = fmaf(tv, c0i[st], c0p);
      h0p = fmaf(tv, h0i[st], h0p);
      c1p = fmaf(tv, c1i[st], c1p);
      h1p = fmaf(tv, h1i[st], h1p);
    }
  }
  bool alive = (ts != 0.0f);
  float inv = 1.0f/(ts + 1e-7f);
  xa*=inv; c0p*=inv; h0p*=inv; c1p*=inv; h1p*=inv;
  if (j==0) pnext[row] = ts;
  xh[rr][j] = xa; xh[rr][256+j] = h0p;
  __syncthreads();
  float c0n=0.f, h0n=0.f;
  if (alive){
    v2f A0={exb[j],0.f}, A1={exb[256+j],0.f}, A2={exb[512+j],0.f}, A3={exb[768+j],0.f};
    #pragma unroll 8
    for (int k2=0;k2<256;k2++){
      v2f hp = *(const v2f*)&xh[rr][2*k2];
      uint4 w = WA[k2*256+j];
      A0 += hp*unpk(w.x); A1 += hp*unpk(w.y);
      A2 += hp*unpk(w.z); A3 += hp*unpk(w.w);
    }
    float a0=A0.x+A0.y, a1=A1.x+A1.y, a2=A2.x+A2.y, a3=A3.x+A3.y;
    c0n = sigf(a1)*c0p + sigf(a0)*tanh_fast(a2);
    h0n = sigf(a3)*tanh_fast(c0n);
  }
  __syncthreads();
  xh[rr][j] = h0n; xh[rr][256+j] = h1p;
  __syncthreads();
  if (alive){
    v2f A0={exb[1024+j],0.f}, A1={exb[1280+j],0.f}, A2={exb[1536+j],0.f}, A3={exb[1792+j],0.f};
    #pragma unroll 8
    for (int k2=0;k2<256;k2++){
      v2f hp = *(const v2f*)&xh[rr][2*k2];
      uint4 w = WB[k2*256+j];
      A0 += hp*unpk(w.x); A1 += hp*unpk(w.y);
      A2 += hp*unpk(w.z); A3 += hp*unpk(w.w);
    }
    float a0=A0.x+A0.y, a1=A1.x+A1.y, a2=A2.x+A2.y, a3=A3.x+A3.y;
    float c1n = sigf(a1)*c1p + sigf(a0)*tanh_fast(a2);
    float h1n = sigf(a3)*tanh_fast(c1n);
    int o = row*256 + j;
    c0o[o]=c0n; h0o[o]=h0n; c1o[o]=c1n; h1o[o]=h1n;
  }
}

// ---------------- K6: out = h_exit @ wo + bo -----------------------------
__global__ __launch_bounds__(256) void k_out(
    const float* __restrict__ h1f, const int* __restrict__ exitIdx,
    const float* __restrict__ wo, const float* __restrict__ bo, float* __restrict__ out){
  __shared__ float hv[8][256];
  int tid = threadIdx.x;
  for (int i = tid; i < 2048; i += 256){
    int b = i >> 8, k = i & 255;
    hv[b][k] = h1f[(b*81 + exitIdx[b])*256 + k];
  }
  __syncthreads();
  int v = blockIdx.x*256 + tid;
  if (v >= 30000) return;
  float acc[8];
  #pragma unroll
  for (int b=0;b<8;b++) acc[b] = bo[v];
  for (int k=0;k<256;k++){
    float w = wo[k*30000 + v];
    #pragma unroll
    for (int b=0;b<8;b++) acc[b] = fmaf(hv[b][k], w, acc[b]);
  }
  #pragma unroll
  for (int b=0;b<8;b++) out[b*30000+v] = acc[b];
}

// ---------------- launch --------------------------------------------------
extern "C" void kernel_launch(void* const* d_in, const int* in_sizes, int n_in,
                              void* d_out, int out_size, void* d_ws, size_t ws_size,
                              hipStream_t stream){
  (void)in_sizes; (void)n_in; (void)out_size;
  const float* ne    = (const float*)d_in[0];
  const int*   exitI = (const int*)d_in[10];
  const float* stWx  = (const float*)d_in[12];
  const float* stb   = (const float*)d_in[14];
  const float* skWx  = (const float*)d_in[15];
  const float* skWh  = (const float*)d_in[16];
  const float* skb   = (const float*)d_in[17];
  const float* lnS   = (const float*)d_in[18];
  const float* lnB   = (const float*)d_in[19];
  const float* exWx  = (const float*)d_in[20];
  const float* exWh  = (const float*)d_in[21];
  const float* exb   = (const float*)d_in[22];
  const float* wk    = (const float*)d_in[23];
  const float* bk    = (const float*)d_in[24];
  const float* wsm   = (const float*)d_in[25];
  const float* bs    = (const float*)d_in[26];
  const float* w1    = (const float*)d_in[27];
  const float* wo    = (const float*)d_in[29];
  const float* bo    = (const float*)d_in[30];
  float* out = (float*)d_out;

  char* w = (char*)d_ws;
  size_t off = 0;
  auto alloc = [&](size_t bytes)->char*{
    char* p = w + off; off += (bytes + 255) & ~size_t(255); return p;
  };
  float4* X0   = (float4*)alloc((size_t)640*256*16);
  u32* W0p2    = (u32*)alloc((size_t)128*1024*4);    // diag(lnS_h0)*Wh0, bf16 packed
  u32* W1p2    = (u32*)alloc((size_t)256*1024*4);    // [Wx1 ; diag(lnS_h1)*Wh1]
  u32* WApk    = (u32*)alloc((size_t)256*1024*4);
  u32* WBpk    = (u32*)alloc((size_t)256*1024*4);
  u32* wkp     = (u32*)alloc((size_t)512*256*4);
  u32* wspk    = (u32*)alloc((size_t)128*256*4);
  float* uv    = (float*)alloc((size_t)5120*4);
  float* skip  = (float*)alloc((size_t)8*81*81*256*4);   // fp32
  u16* keys    = (u16*)alloc((size_t)8*81*81*256*2);     // bf16
  float* tb    = (float*)alloc((size_t)ROWS*81*4);
  float* p0    = (float*)alloc(ROWS*4);
  float* p1    = (float*)alloc(ROWS*4);
  float* stA   = (float*)alloc((size_t)4*ROWS*256*4);
  float* stB   = (float*)alloc((size_t)4*ROWS*256*4);
  float* H0a   = (float*)alloc((size_t)640*256*4);
  float* H0b   = (float*)alloc((size_t)640*256*4);
  float* H1a   = (float*)alloc((size_t)640*256*4);
  float* H1b   = (float*)alloc((size_t)640*256*4);
  float* stats = (float*)alloc((size_t)80*640*2*4);
  if (off > ws_size) return;   // workspace too small — surfaces as absmax fail

  const size_t ST = (size_t)ROWS*256;
  float *A_c0=stA, *A_h0=stA+ST, *A_c1=stA+2*ST, *A_h1=stA+3*ST;
  float *B_c0=stB, *B_h0=stB+ST, *B_c1=stB+2*ST, *B_h1=stB+3*ST;

  hipMemsetAsync(skip, 0, (size_t)8*81*81*256*4, stream);
  hipMemsetAsync(stats, 0, (size_t)80*640*2*4, stream);
  hipMemsetAsync(stA, 0, (size_t)4*ROWS*256*4, stream);
  hipMemsetAsync(stB, 0, (size_t)4*ROWS*256*4, stream);
  k_init_p<<<3,256,0,stream>>>(p0);

  pack_gates_sc<<<512, 256, 0, stream>>>(skWh, skWh, lnS+256, nullptr, W0p2, 256);
  pack_gates_sc<<<1024,256, 0, stream>>>(skWx+256*1024, skWh+256*1024, nullptr, lnS+768, W1p2, 512);
  pack_gates<<<1024,256, 0, stream>>>(exWx, exWh, WApk, 512);
  pack_gates<<<1024,256, 0, stream>>>(exWx+256*1024, exWh+256*1024, WBpk, 512);
  pack_pairs<<<512, 256, 0, stream>>>(wk, wkp, 512, 256);
  pack_pairs<<<128, 256, 0, stream>>>(wsm, wspk, 128, 256);
  k_uv<<<4, 256, 0, stream>>>(skWh, skWh+256*1024, lnS, lnB, skb, uv);

  k_stmt_x0<<<320, 512, 0, stream>>>(ne, stWx, stb, skWx, skb, X0);

  // one cooperative launch for all 80 wavefront steps
  {
    const float4* X0c = (const float4*)X0;
    const uint4* W0c = (const uint4*)W0p2;
    const uint4* W1c = (const uint4*)W1p2;
    const float4* uvc = (const float4*)uv;
    const float* lnSc = lnS; const float* lnBc = lnB;
    void* args[] = { (void*)&X0c, (void*)&W0c, (void*)&W1c, (void*)&uvc,
                     (void*)&lnSc, (void*)&lnBc,
                     (void*)&H0a, (void*)&H0b, (void*)&H1a, (void*)&H1b,
                     (void*)&stats, (void*)&skip };
    hipLaunchCooperativeKernel((const void*)k_chain_coop, dim3(256), dim3(512),
                               args, 0, stream);
  }

  k_keys<<<648, 256, 0, stream>>>(skip, wspk, bs, keys);

  float* pc = p0; float* pn = p1;
  for (int s=0; s<8; s++){
    float *ic0,*ih0,*ic1,*ih1,*oc0,*oh0,*oc1,*oh1;
    if ((s & 1) == 0){ ic0=A_c0; ih0=A_h0; ic1=A_c1; ih1=A_h1; oc0=B_c0; oh0=B_h0; oc1=B_c1; oh1=B_h1; }
    else             { ic0=B_c0; ih0=B_h0; ic1=B_c1; ih1=B_h1; oc0=A_c0; oh0=A_h0; oc1=A_c1; oh1=A_h1; }
    int mode = (s==0) ? 0 : ((s==7) ? 2 : 1);
    k_attn<<<648, 256, 0, stream>>>(ic0, ih0, ic1, ih1, wkp, bk, keys, w1, pc, tb, mode);
    k_update<<<162, 1024, 0, stream>>>(tb, skip, ic0, ih0, ic1, ih1,
                                       (const uint4*)WApk, (const uint4*)WBpk, exb,
                                       oc0, oh0, oc1, oh1, pn);
    float* tmp = pc; pc = pn; pn = tmp;
  }
  // final states are in buffer A (step 7 writes A)
  k_out<<<(30000+255)/256, 256, 0, stream>>>(A_h1, exitI, wo, bo, out);
}

// Round 9
// 3834.695 us; speedup vs baseline: 2.1138x; 2.1138x over previous
//
#include <hip/hip_runtime.h>

typedef unsigned int  u32;
typedef unsigned short u16;
typedef float v2f __attribute__((ext_vector_type(2)));

// B=8, NS=80, NN=81, H=256, L=2, STEPS=8, VOCAB=30000
#define ROWS 648          // B*NN

__device__ __forceinline__ float sigf(float x){ return 1.0f/(1.0f+__expf(-x)); }
__device__ __forceinline__ float tanh_fast(float x){
  float e = __expf(-2.0f*fabsf(x));
  float r = (1.0f-e)/(1.0f+e);
  return copysignf(r,x);
}
__device__ __forceinline__ u16 f2bf(float f){        // RTNE f32->bf16
  u32 u = __float_as_uint(f);
  u += 0x7FFFu + ((u>>16)&1u);
  return (u16)(u>>16);
}
__device__ __forceinline__ u32 packbf2(float lo, float hi){
  return (u32)f2bf(lo) | ((u32)f2bf(hi)<<16);
}
__device__ __forceinline__ float bf2f(u16 v){ return __uint_as_float(((u32)v)<<16); }
__device__ __forceinline__ float bflo(u32 u){ return __uint_as_float(u<<16); }
__device__ __forceinline__ float bfhi(u32 u){ return __uint_as_float(u & 0xFFFF0000u); }
__device__ __forceinline__ v2f unpk(u32 w){
  v2f r; r.x = bflo(w); r.y = bfhi(w); return r;
}

// ---------------- weight packing ----------------------------------------
// gate-quad, k-pair layout: dst[k2*1024 + j*4 + g] = pack(src[2k2][g*256+j], src[2k2+1][g*256+j])
__global__ void pack_gates(const float* __restrict__ A, const float* __restrict__ Bm,
                           u32* __restrict__ dst, int Krows){
  int id = blockIdx.x*256 + threadIdx.x;
  int tot = (Krows>>1)*1024;
  if (id >= tot) return;
  int k2 = id >> 10;
  int c  = id & 1023;
  int j = c >> 2, g = c & 3;
  int k0 = 2*k2, k1 = 2*k2+1;
  float v0 = (k0<256) ? A[k0*1024 + g*256 + j] : Bm[(k0-256)*1024 + g*256 + j];
  float v1 = (k1<256) ? A[k1*1024 + g*256 + j] : Bm[(k1-256)*1024 + g*256 + j];
  dst[id] = packbf2(v0, v1);
}

// scaled variant: rows k<256 from A (scaled by scA), k>=256 from Bm (scaled by scB)
__global__ void pack_gates_sc(const float* __restrict__ A, const float* __restrict__ Bm,
                              const float* __restrict__ scA, const float* __restrict__ scB,
                              u32* __restrict__ dst, int Krows){
  int id = blockIdx.x*256 + threadIdx.x;
  int tot = (Krows>>1)*1024;
  if (id >= tot) return;
  int k2 = id >> 10;
  int c  = id & 1023;
  int j = c >> 2, g = c & 3;
  int k0 = 2*k2, k1 = 2*k2+1;
  float v0, v1;
  if (k0 < 256){ v0 = A[k0*1024 + g*256 + j];        if (scA) v0 *= scA[k0]; }
  else         { v0 = Bm[(k0-256)*1024 + g*256 + j]; if (scB) v0 *= scB[k0-256]; }
  if (k1 < 256){ v1 = A[k1*1024 + g*256 + j];        if (scA) v1 *= scA[k1]; }
  else         { v1 = Bm[(k1-256)*1024 + g*256 + j]; if (scB) v1 *= scB[k1-256]; }
  dst[id] = packbf2(v0, v1);
}

__global__ void pack_pairs(const float* __restrict__ src, u32* __restrict__ dst,
                           int Kpairs, int ncol){
  int id = blockIdx.x*256 + threadIdx.x;
  if (id >= Kpairs*ncol) return;
  int k2 = id / ncol, j = id - k2*ncol;
  dst[id] = packbf2(src[(2*k2)*ncol + j], src[(2*k2+1)*ncol + j]);
}

__global__ void k_init_p(float* __restrict__ p0){
  int i = blockIdx.x*256 + threadIdx.x;
  if (i < ROWS) p0[i] = ((i % 81)==0) ? 1.0f : 0.0f;
}

// LN-fold constants: uv[jh*4+g]: u0 | v0(+1024) | u1(+2048) | v1(+3072) | cb1(+4096)
__global__ void k_uv(const float* __restrict__ Wh0, const float* __restrict__ Wh1,
                     const float* __restrict__ lnS, const float* __restrict__ lnB,
                     const float* __restrict__ skb, float* __restrict__ uv){
  int id = blockIdx.x*256 + threadIdx.x;       // 0..1023
  int g = id & 3, jh = id >> 2;
  float u0=0,v0=0,u1=0,v1=0;
  for (int k=0;k<256;k++){
    float w0 = Wh0[k*1024 + g*256 + jh];
    u0 = fmaf(lnS[256+k], w0, u0); v0 = fmaf(lnB[256+k], w0, v0);
    float w1 = Wh1[k*1024 + g*256 + jh];
    u1 = fmaf(lnS[768+k], w1, u1); v1 = fmaf(lnB[768+k], w1, v1);
  }
  uv[id]=u0; uv[1024+id]=v0; uv[2048+id]=u1; uv[3072+id]=v1;
  uv[4096+id]=skb[1024 + g*256 + jh];
}

// ---------------- K1: statement embedder + X0 precompute ----------------
__global__ __launch_bounds__(512) void k_stmt_x0(
    const float* __restrict__ ne, const float* __restrict__ stWx, const float* __restrict__ stb,
    const float* __restrict__ skWx, const float* __restrict__ skb, float4* __restrict__ X0){
  __shared__ float xv[2][256];
  __shared__ float hv[2][256];
  int r = threadIdx.x >> 8, j = threadIdx.x & 255;
  int bn = blockIdx.x*2 + r;                    // 0..639
  xv[r][j] = ne[bn*256 + j];
  __syncthreads();
  float a0=stb[j], a2=stb[512+j], a3=stb[768+j];
  for (int k=0;k<256;k++){
    float x = xv[r][k];
    const float* w = stWx + k*1024;
    a0 = fmaf(x, w[j], a0); a2 = fmaf(x, w[512+j], a2); a3 = fmaf(x, w[768+j], a3);
  }
  float c = sigf(a0)*tanh_fast(a2);
  float h = sigf(a3)*tanh_fast(c);
  hv[r][j] = h;
  __syncthreads();
  a0=stb[1024+j]; a2=stb[1536+j]; a3=stb[1792+j];
  const float* W1 = stWx + 256*1024;
  for (int k=0;k<256;k++){
    float x = hv[r][k];
    const float* w = W1 + k*1024;
    a0 = fmaf(x, w[j], a0); a2 = fmaf(x, w[512+j], a2); a3 = fmaf(x, w[768+j], a3);
  }
  c = sigf(a0)*tanh_fast(a2);
  h = sigf(a3)*tanh_fast(c);
  __syncthreads();
  xv[r][j] = h;           // stmt row
  __syncthreads();
  float b0=skb[j], b1g=skb[256+j], b2=skb[512+j], b3=skb[768+j];
  for (int k=0;k<256;k++){
    float x = xv[r][k];
    const float* w = skWx + k*1024;
    b0 = fmaf(x, w[j], b0);     b1g = fmaf(x, w[256+j], b1g);
    b2 = fmaf(x, w[512+j], b2); b3 = fmaf(x, w[768+j], b3);
  }
  X0[bn*256 + j] = make_float4(b0,b1g,b2,b3);
}

// ---------------- K3: skip-encoder chains (r4' : folded LN, 4 barriers) --
// grid = 160 (80 s x 2 batch-halves); 1024 thr.
//   matvec role: tid = kh*256+j — weight uint4 loaded once, serves 4 rows.
//   cell role:   tid = rr*256+j — gates from partials, cell, stats.
// LN folded into weights: h_ln@W = rstd*(h_raw@diag(lnS)W) - rstd*mu*u + v.
// Raw h0/h1 in LDS; mu/rstd from prev step's shuffle-reduced stats (red).
__global__ __launch_bounds__(1024) void k_skip_chains(
    const float4* __restrict__ X0,
    const uint4* __restrict__ W0p, const uint4* __restrict__ W1p,
    const float4* __restrict__ uv4, const float* __restrict__ lnS, const float* __restrict__ lnB,
    float* __restrict__ skip){
  int s  = blockIdx.x >> 1;
  int bh = blockIdx.x & 1;
  int tid = threadIdx.x;
  int kh = tid >> 8, j = tid & 255;     // matvec role
  int rr = kh;                          // cell role row
  int b  = bh*4 + rr;
  __shared__ float part[16384];         // 64KB [(kh*4+r4)*4+g][j]
  __shared__ float h0raw[1024];         // [k2*8 + row*2 + par], k2<128
  __shared__ float in1raw[2048];        // [k2*8 + row*2 + par], k2<256 (h0|h1)
  __shared__ float red[4][8];
  __shared__ float rstdS[4];
  float c0=0.f, c1=0.f;
  float lc0s = lnS[j], lc0b = lnB[j];
  float lc1s = lnS[512+j], lc1b = lnB[512+j];
  float mu=0.f, rstd=0.f;
  for (int idx=s; idx<80; idx++){
    bool start = (idx == s);
    float4 gx = X0[(b*80+idx)*256 + j];       // this thread's cell-role X0
    // ---- M0: h0_raw @ W0ln, k2 slice [kh*32, +32)
    if (!start){
      v2f acc[4][4];
      #pragma unroll
      for (int r4=0;r4<4;r4++){
        #pragma unroll
        for (int g=0;g<4;g++) acc[r4][g]=(v2f){0.f,0.f};
      }
      #pragma unroll 4
      for (int i=0;i<32;i++){
        int k2 = kh*32+i;
        uint4 w = W0p[k2*256 + j];
        v2f w0=unpk(w.x), w1=unpk(w.y), w2=unpk(w.z), w3=unpk(w.w);
        const float* hb = &h0raw[k2*8];
        #pragma unroll
        for (int r4=0;r4<4;r4++){
          v2f hp = *(const v2f*)&hb[r4*2];
          acc[r4][0]+=hp*w0; acc[r4][1]+=hp*w1; acc[r4][2]+=hp*w2; acc[r4][3]+=hp*w3;
        }
      }
      #pragma unroll
      for (int r4=0;r4<4;r4++){
        #pragma unroll
        for (int g=0;g<4;g++)
          part[((kh*4+r4)*4+g)*256 + j] = acc[r4][g].x + acc[r4][g].y;
      }
    }
    __syncthreads();                                    // S1
    // ---- C0: layer0 cell (row rr, col j)
    float a0,a1,a2,a3;
    if (start){
      mu=0.f; rstd=0.f;
      a0=gx.x; a1=gx.y; a2=gx.z; a3=gx.w;
    } else {
      float sm = red[rr][0]+red[rr][1]+red[rr][2]+red[rr][3];
      float sq = red[rr][4]+red[rr][5]+red[rr][6]+red[rr][7];
      mu = sm * (1.0f/1024.0f);
      float var = sq * (1.0f/1024.0f) - mu*mu;
      rstd = rsqrtf(var + 1e-6f);
      if (j == 0) rstdS[rr] = rstd;
      float P0=0,P1=0,P2=0,P3=0;
      #pragma unroll
      for (int k=0;k<4;k++){
        P0 += part[((k*4+rr)*4+0)*256+j];
        P1 += part[((k*4+rr)*4+1)*256+j];
        P2 += part[((k*4+rr)*4+2)*256+j];
        P3 += part[((k*4+rr)*4+3)*256+j];
      }
      float4 u0 = uv4[j], v0 = uv4[256+j];
      float rm = rstd*mu;
      a0 = gx.x + rstd*P0 - rm*u0.x + v0.x;
      a1 = gx.y + rstd*P1 - rm*u0.y + v0.y;
      a2 = gx.z + rstd*P2 - rm*u0.z + v0.z;
      a3 = gx.w + rstd*P3 - rm*u0.w + v0.w;
    }
    float c0ln = start ? 0.f : (c0 - mu)*rstd*lc0s + lc0b;
    float ii=sigf(a0), ff=sigf(a1), gg=tanh_fast(a2), oo=sigf(a3);
    c0 = ff*c0ln + ii*gg;
    float h0v = oo*tanh_fast(c0);
    h0raw[(j>>1)*8 + rr*2 + (j&1)] = h0v;         // next step's M0 input
    in1raw[(j>>1)*8 + rr*2 + (j&1)] = h0v;        // this step's M1 input (h0 half)
    __syncthreads();                                    // S2
    // ---- M1: [h0_raw | h1_raw] @ [Wx1 ; W1ln], k2 slice [kh*64, +64)
    {
      v2f acc[4][4];
      #pragma unroll
      for (int r4=0;r4<4;r4++){
        #pragma unroll
        for (int g=0;g<4;g++) acc[r4][g]=(v2f){0.f,0.f};
      }
      bool active = (!start) || (kh < 2);       // h1 half is zero on start steps
      if (active){
        #pragma unroll 4
        for (int i=0;i<64;i++){
          int k2 = kh*64+i;
          uint4 w = W1p[k2*256 + j];
          v2f w0=unpk(w.x), w1=unpk(w.y), w2=unpk(w.z), w3=unpk(w.w);
          const float* hb = &in1raw[k2*8];
          #pragma unroll
          for (int r4=0;r4<4;r4++){
            v2f hp = *(const v2f*)&hb[r4*2];
            acc[r4][0]+=hp*w0; acc[r4][1]+=hp*w1; acc[r4][2]+=hp*w2; acc[r4][3]+=hp*w3;
          }
        }
      }
      if (kh >= 2 && !start){
        // h1-folded half: scale by per-row rstd before writing partials
        #pragma unroll
        for (int r4=0;r4<4;r4++){
          float rs = rstdS[r4];
          #pragma unroll
          for (int g=0;g<4;g++)
            part[((kh*4+r4)*4+g)*256 + j] = (acc[r4][g].x + acc[r4][g].y)*rs;
        }
      } else {
        #pragma unroll
        for (int r4=0;r4<4;r4++){
          #pragma unroll
          for (int g=0;g<4;g++)
            part[((kh*4+r4)*4+g)*256 + j] = acc[r4][g].x + acc[r4][g].y;
        }
      }
    }
    __syncthreads();                                    // S3
    // ---- C1: layer1 cell + skip + stats (row rr, col j)
    {
      float P0=0,P1=0,P2=0,P3=0;
      #pragma unroll
      for (int k=0;k<4;k++){
        P0 += part[((k*4+rr)*4+0)*256+j];
        P1 += part[((k*4+rr)*4+1)*256+j];
        P2 += part[((k*4+rr)*4+2)*256+j];
        P3 += part[((k*4+rr)*4+3)*256+j];
      }
      float4 cbv = uv4[1024+j];
      a0 = P0 + cbv.x; a1 = P1 + cbv.y; a2 = P2 + cbv.z; a3 = P3 + cbv.w;
      if (!start){
        float4 u1 = uv4[512+j], v1 = uv4[768+j];
        float rm = rstd*mu;
        a0 += -rm*u1.x + v1.x;
        a1 += -rm*u1.y + v1.y;
        a2 += -rm*u1.z + v1.z;
        a3 += -rm*u1.w + v1.w;
      }
      float c1ln = start ? 0.f : (c1 - mu)*rstd*lc1s + lc1b;
      float ii=sigf(a0), ff=sigf(a1), gg=tanh_fast(a2), oo=sigf(a3);
      c1 = ff*c1ln + ii*gg;
      float h1v = oo*tanh_fast(c1);
      skip[((b*81 + s)*81 + (idx+1))*256 + j] = h1v;    // pre-LN output
      in1raw[(128+(j>>1))*8 + rr*2 + (j&1)] = h1v;      // next step's M1 h1-half
      float h0v = in1raw[(j>>1)*8 + rr*2 + (j&1)];
      float sm = c0 + h0v + c1 + h1v;
      float sq = c0*c0 + h0v*h0v + c1*c1 + h1v*h1v;
      #pragma unroll
      for (int off=32; off; off>>=1){ sm += __shfl_xor(sm, off); sq += __shfl_xor(sq, off); }
      int wq = j >> 6;
      if ((j & 63) == 0){ red[rr][wq] = sm; red[rr][4+wq] = sq; }
    }
    __syncthreads();                                    // S4
  }
}

// ---------------- K4: keys = skip @ ws + bs  (bf16 out) ------------------
__global__ __launch_bounds__(256) void k_keys(const float* __restrict__ skip,
    const u32* __restrict__ wspk, const float* __restrict__ bs, u16* __restrict__ keys){
  __shared__ float skr[8][256];
  int tid = threadIdx.x;
  int bn = blockIdx.x;
  float bsv = bs[tid];
  const float4* sk4 = (const float4*)skip;
  for (int m0=0; m0<81; m0+=8){
    int mc = (81-m0 < 8) ? (81-m0) : 8;
    for (int i=tid; i<mc*64; i+=256){
      int mm = i>>6, kk = i&63;
      float4 v = sk4[(bn*81 + m0 + mm)*64 + kk];
      skr[mm][4*kk+0]=v.x; skr[mm][4*kk+1]=v.y; skr[mm][4*kk+2]=v.z; skr[mm][4*kk+3]=v.w;
    }
    __syncthreads();
    v2f acc[8];
    #pragma unroll
    for (int qq=0;qq<8;qq++) acc[qq]=(v2f){0.f,0.f};
    for (int k2=0;k2<128;k2++){
      v2f w2 = unpk(wspk[k2*256+tid]);
      #pragma unroll
      for (int qq=0;qq<8;qq++){
        v2f sv = *(const v2f*)&skr[qq][2*k2];
        acc[qq] += sv*w2;
      }
    }
    for (int qq=0;qq<mc;qq++) keys[(bn*81+m0+qq)*256+tid] = f2bf(acc[qq].x+acc[qq].y+bsv);
    __syncthreads();
  }
}

// ---------------- Kb: fused q + logits -> softmax -> t -------------------
__global__ __launch_bounds__(256) void k_attn(
    const float* __restrict__ c0g, const float* __restrict__ h0g,
    const float* __restrict__ c1g, const float* __restrict__ h1g,
    const u32* __restrict__ wkp, const float* __restrict__ bk,
    const u16* __restrict__ keys, const float* __restrict__ w1,
    const float* __restrict__ pcur, float* __restrict__ t, int mode){
  int bn = blockIdx.x; int n = bn % 81;
  int tid = threadIdx.x;
  float pv = pcur[bn];
  if (pv == 0.0f){
    if (tid < 81) t[bn*81 + tid] = 0.0f;
    return;
  }
  __shared__ float hc[1024];
  __shared__ float qv[256];
  __shared__ float lg[81];
  hc[tid]      = c0g[bn*256+tid];
  hc[256+tid]  = h0g[bn*256+tid];
  hc[512+tid]  = c1g[bn*256+tid];
  hc[768+tid]  = h1g[bn*256+tid];
  if (tid < 81) lg[tid] = -3e38f;
  __syncthreads();
  v2f A = {bk[tid], 0.f};
  #pragma unroll 8
  for (int k2=0;k2<512;k2++){
    v2f hp = *(const v2f*)&hc[2*k2];
    A += hp*unpk(wkp[k2*256+tid]);
  }
  qv[tid] = A.x + A.y;
  __syncthreads();
  int lane = tid & 63, wv = tid >> 6;
  float w1v0 = w1[lane], w1v1 = w1[64+lane], w1v2 = w1[128+lane], w1v3 = w1[192+lane];
  for (int m = wv; m < 81; m += 4){
    bool um = (mode==0) ? (m==1) : (mode==2) ? (m==80) : (m>n || m==80);
    if (!um) continue;
    const u16* kr = keys + (bn*81+m)*256;
    float acc;
    acc  = tanh_fast(qv[lane]     + bf2f(kr[lane]))     * w1v0;
    acc += tanh_fast(qv[64+lane]  + bf2f(kr[64+lane]))  * w1v1;
    acc += tanh_fast(qv[128+lane] + bf2f(kr[128+lane])) * w1v2;
    acc += tanh_fast(qv[192+lane] + bf2f(kr[192+lane])) * w1v3;
    #pragma unroll
    for (int off=32; off; off>>=1) acc += __shfl_xor(acc, off);
    if (lane==0) lg[m] = acc;      // b1 omitted: softmax-invariant
  }
  __syncthreads();
  if (tid < 64){
    float v1 = lg[tid];
    float v2 = (tid<17) ? lg[64+tid] : -3e38f;
    float mx = fmaxf(v1, v2);
    #pragma unroll
    for (int off=32; off; off>>=1) mx = fmaxf(mx, __shfl_xor(mx, off));
    float e1 = __expf(v1-mx);
    float e2 = (tid<17) ? __expf(v2-mx) : 0.0f;
    float ssum = e1+e2;
    #pragma unroll
    for (int off=32; off; off>>=1) ssum += __shfl_xor(ssum, off);
    float sc = pv / ssum;
    t[bn*81 + tid] = e1*sc;
    if (tid<17) t[bn*81 + 64+tid] = e2*sc;
  }
}

// ---------------- Kc: x_in/prop einsums + ex-LSTM step + new_p -----------
__global__ __launch_bounds__(1024) void k_update(
    const float* __restrict__ t, const float* __restrict__ skip,
    const float* __restrict__ c0i, const float* __restrict__ h0i,
    const float* __restrict__ c1i, const float* __restrict__ h1i,
    const uint4* __restrict__ WA, const uint4* __restrict__ WB,
    const float* __restrict__ exb,
    float* __restrict__ c0o, float* __restrict__ h0o,
    float* __restrict__ c1o, float* __restrict__ h1o,
    float* __restrict__ pnext){
  int rr = threadIdx.x >> 8, j = threadIdx.x & 255;
  int row = blockIdx.x*4 + rr;
  int b = row / 81, m = row - b*81;
  __shared__ float tcol[4][81];
  __shared__ float xh[4][512];
  if (j < 81) tcol[rr][j] = t[(b*81 + j)*81 + m];
  __syncthreads();
  float xa=0.f, c0p=0.f, h0p=0.f, c1p=0.f, h1p=0.f, ts=0.f;
  for (int n=0;n<81;n++){
    float tv = tcol[rr][n];
    ts += tv;
    if (tv != 0.0f){
      xa  = fmaf(tv, skip[((b*81+n)*81 + m)*256 + j], xa);
      int st = (b*81+n)*256 + j;
      c0p = fmaf(tv, c0i[st], c0p);
      h0p = fmaf(tv, h0i[st], h0p);
      c1p = fmaf(tv, c1i[st], c1p);
      h1p = fmaf(tv, h1i[st], h1p);
    }
  }
  bool alive = (ts != 0.0f);
  float inv = 1.0f/(ts + 1e-7f);
  xa*=inv; c0p*=inv; h0p*=inv; c1p*=inv; h1p*=inv;
  if (j==0) pnext[row] = ts;
  xh[rr][j] = xa; xh[rr][256+j] = h0p;
  __syncthreads();
  float c0n=0.f, h0n=0.f;
  if (alive){
    v2f A0={exb[j],0.f}, A1={exb[256+j],0.f}, A2={exb[512+j],0.f}, A3={exb[768+j],0.f};
    #pragma unroll 8
    for (int k2=0;k2<256;k2++){
      v2f hp = *(const v2f*)&xh[rr][2*k2];
      uint4 w = WA[k2*256+j];
      A0 += hp*unpk(w.x); A1 += hp*unpk(w.y);
      A2 += hp*unpk(w.z); A3 += hp*unpk(w.w);
    }
    float a0=A0.x+A0.y, a1=A1.x+A1.y, a2=A2.x+A2.y, a3=A3.x+A3.y;
    c0n = sigf(a1)*c0p + sigf(a0)*tanh_fast(a2);
    h0n = sigf(a3)*tanh_fast(c0n);
  }
  __syncthreads();
  xh[rr][j] = h0n; xh[rr][256+j] = h1p;
  __syncthreads();
  if (alive){
    v2f A0={exb[1024+j],0.f}, A1={exb[1280+j],0.f}, A2={exb[1536+j],0.f}, A3={exb[1792+j],0.f};
    #pragma unroll 8
    for (int k2=0;k2<256;k2++){
      v2f hp = *(const v2f*)&xh[rr][2*k2];
      uint4 w = WB[k2*256+j];
      A0 += hp*unpk(w.x); A1 += hp*unpk(w.y);
      A2 += hp*unpk(w.z); A3 += hp*unpk(w.w);
    }
    float a0=A0.x+A0.y, a1=A1.x+A1.y, a2=A2.x+A2.y, a3=A3.x+A3.y;
    float c1n = sigf(a1)*c1p + sigf(a0)*tanh_fast(a2);
    float h1n = sigf(a3)*tanh_fast(c1n);
    int o = row*256 + j;
    c0o[o]=c0n; h0o[o]=h0n; c1o[o]=c1n; h1o[o]=h1n;
  }
}

// ---------------- K6: out = h_exit @ wo + bo -----------------------------
__global__ __launch_bounds__(256) void k_out(
    const float* __restrict__ h1f, const int* __restrict__ exitIdx,
    const float* __restrict__ wo, const float* __restrict__ bo, float* __restrict__ out){
  __shared__ float hv[8][256];
  int tid = threadIdx.x;
  for (int i = tid; i < 2048; i += 256){
    int b = i >> 8, k = i & 255;
    hv[b][k] = h1f[(b*81 + exitIdx[b])*256 + k];
  }
  __syncthreads();
  int v = blockIdx.x*256 + tid;
  if (v >= 30000) return;
  float acc[8];
  #pragma unroll
  for (int b=0;b<8;b++) acc[b] = bo[v];
  for (int k=0;k<256;k++){
    float w = wo[k*30000 + v];
    #pragma unroll
    for (int b=0;b<8;b++) acc[b] = fmaf(hv[b][k], w, acc[b]);
  }
  #pragma unroll
  for (int b=0;b<8;b++) out[b*30000+v] = acc[b];
}

// ---------------- launch --------------------------------------------------
extern "C" void kernel_launch(void* const* d_in, const int* in_sizes, int n_in,
                              void* d_out, int out_size, void* d_ws, size_t ws_size,
                              hipStream_t stream){
  (void)in_sizes; (void)n_in; (void)out_size;
  const float* ne    = (const float*)d_in[0];
  const int*   exitI = (const int*)d_in[10];
  const float* stWx  = (const float*)d_in[12];
  const float* stb   = (const float*)d_in[14];
  const float* skWx  = (const float*)d_in[15];
  const float* skWh  = (const float*)d_in[16];
  const float* skb   = (const float*)d_in[17];
  const float* lnS   = (const float*)d_in[18];
  const float* lnB   = (const float*)d_in[19];
  const float* exWx  = (const float*)d_in[20];
  const float* exWh  = (const float*)d_in[21];
  const float* exb   = (const float*)d_in[22];
  const float* wk    = (const float*)d_in[23];
  const float* bk    = (const float*)d_in[24];
  const float* wsm   = (const float*)d_in[25];
  const float* bs    = (const float*)d_in[26];
  const float* w1    = (const float*)d_in[27];
  const float* wo    = (const float*)d_in[29];
  const float* bo    = (const float*)d_in[30];
  float* out = (float*)d_out;

  char* w = (char*)d_ws;
  size_t off = 0;
  auto alloc = [&](size_t bytes)->char*{
    char* p = w + off; off += (bytes + 255) & ~size_t(255); return p;
  };
  float4* X0   = (float4*)alloc((size_t)640*256*16);
  u32* W0p2    = (u32*)alloc((size_t)128*1024*4);    // diag(lnS_h0)*Wh0, bf16 packed
  u32* W1p2    = (u32*)alloc((size_t)256*1024*4);    // [Wx1 ; diag(lnS_h1)*Wh1]
  u32* WApk    = (u32*)alloc((size_t)256*1024*4);
  u32* WBpk    = (u32*)alloc((size_t)256*1024*4);
  u32* wkp     = (u32*)alloc((size_t)512*256*4);
  u32* wspk    = (u32*)alloc((size_t)128*256*4);
  float* uv    = (float*)alloc((size_t)5120*4);
  float* skip  = (float*)alloc((size_t)8*81*81*256*4);   // fp32
  u16* keys    = (u16*)alloc((size_t)8*81*81*256*2);     // bf16
  float* tb    = (float*)alloc((size_t)ROWS*81*4);
  float* p0    = (float*)alloc(ROWS*4);
  float* p1    = (float*)alloc(ROWS*4);
  float* stA   = (float*)alloc((size_t)4*ROWS*256*4);
  float* stB   = (float*)alloc((size_t)4*ROWS*256*4);
  if (off > ws_size) return;   // workspace too small — surfaces as absmax fail

  const size_t ST = (size_t)ROWS*256;
  float *A_c0=stA, *A_h0=stA+ST, *A_c1=stA+2*ST, *A_h1=stA+3*ST;
  float *B_c0=stB, *B_h0=stB+ST, *B_c1=stB+2*ST, *B_h1=stB+3*ST;

  hipMemsetAsync(skip, 0, (size_t)8*81*81*256*4, stream);
  hipMemsetAsync(stA, 0, (size_t)4*ROWS*256*4, stream);
  hipMemsetAsync(stB, 0, (size_t)4*ROWS*256*4, stream);
  k_init_p<<<3,256,0,stream>>>(p0);

  pack_gates_sc<<<512, 256, 0, stream>>>(skWh, skWh, lnS+256, nullptr, W0p2, 256);
  pack_gates_sc<<<1024,256, 0, stream>>>(skWx+256*1024, skWh+256*1024, nullptr, lnS+768, W1p2, 512);
  pack_gates<<<1024,256, 0, stream>>>(exWx, exWh, WApk, 512);
  pack_gates<<<1024,256, 0, stream>>>(exWx+256*1024, exWh+256*1024, WBpk, 512);
  pack_pairs<<<512, 256, 0, stream>>>(wk, wkp, 512, 256);
  pack_pairs<<<128, 256, 0, stream>>>(wsm, wspk, 128, 256);
  k_uv<<<4, 256, 0, stream>>>(skWh, skWh+256*1024, lnS, lnB, skb, uv);

  k_stmt_x0<<<320, 512, 0, stream>>>(ne, stWx, stb, skWx, skb, X0);
  k_skip_chains<<<160, 1024, 0, stream>>>(X0, (const uint4*)W0p2, (const uint4*)W1p2,
                                          (const float4*)uv, lnS, lnB, skip);
  k_keys<<<648, 256, 0, stream>>>(skip, wspk, bs, keys);

  float* pc = p0; float* pn = p1;
  for (int s=0; s<8; s++){
    float *ic0,*ih0,*ic1,*ih1,*oc0,*oh0,*oc1,*oh1;
    if ((s & 1) == 0){ ic0=A_c0; ih0=A_h0; ic1=A_c1; ih1=A_h1; oc0=B_c0; oh0=B_h0; oc1=B_c1; oh1=B_h1; }
    else             { ic0=B_c0; ih0=B_h0; ic1=B_c1; ih1=B_h1; oc0=A_c0; oh0=A_h0; oc1=A_c1; oh1=A_h1; }
    int mode = (s==0) ? 0 : ((s==7) ? 2 : 1);
    k_attn<<<648, 256, 0, stream>>>(ic0, ih0, ic1, ih1, wkp, bk, keys, w1, pc, tb, mode);
    k_update<<<162, 1024, 0, stream>>>(tb, skip, ic0, ih0, ic1, ih1,
                                       (const uint4*)WApk, (const uint4*)WBpk, exb,
                                       oc0, oh0, oc1, oh1, pn);
    float* tmp = pc; pc = pn; pn = tmp;
  }
  // final states are in buffer A (step 7 writes A)
  k_out<<<(30000+255)/256, 256, 0, stream>>>(A_h1, exitI, wo, bo, out);
}